// Round 5
// baseline (2457.407 us; speedup 1.0000x reference)
//
#include <hip/hip_runtime.h>
#include <math.h>

// ---------------------------------------------------------------------------
// BDH forward, MI355X. Round 5: round-3 MFMA fast path + THE fix:
// d_out is FLOAT32 (reference returns fp32 logits; rounds 1/3/4 failed with
// absmax ~= sqrt(2)*ref_absmax purely because logits were stored as bf16 —
// checker read packed bf16 pairs as fp32 => decorrelated halves + zero tail).
// Inputs: idx int32; embed/encoder/encoder_v/decoder/lm_head fp32 (round-2
// bf16-read NaN + rounds-1/3/4 finite fp32 reads pin the storage dtype).
//
// gemm_bt: C = A(MxK) * Bt(NxK)^T, 128x128 tile, BK=32, 4 waves x (4x4)
// mfma_f32_16x16x32_bf16, fp32 accum. Layouts (learn_hip m89/m91):
//   A: lane m=l%16, k=8*(l/16)+e ; B: lane n=l%16, k=8*(l/16)+e
//   D: lane reg r: row=4*(l/16)+r, col=l%16
// ---------------------------------------------------------------------------

typedef __bf16 bf16;
typedef bf16  bf16x8 __attribute__((ext_vector_type(8)));
typedef float f32x4  __attribute__((ext_vector_type(4)));

#define BM 128
#define BN 128
#define BK 32

__device__ __forceinline__ float bf2f(unsigned short u) {
  unsigned int x = ((unsigned int)u) << 16;
  return __builtin_bit_cast(float, x);
}
__device__ __forceinline__ unsigned short f2bf_bits(float f) {
  bf16 b = (bf16)f;
  return __builtin_bit_cast(unsigned short, b);
}

__device__ __forceinline__ float block_sum256(float v) {
  __shared__ float sb[4];
#pragma unroll
  for (int o = 32; o > 0; o >>= 1) v += __shfl_down(v, o);
  __syncthreads();
  if ((threadIdx.x & 63) == 0) sb[threadIdx.x >> 6] = v;
  __syncthreads();
  return sb[0] + sb[1] + sb[2] + sb[3];
}

// MODE 1: relu + bf16 store
// MODE 2: strict causal mask (col<row), bf16 store; tiles above diagonal skipped
// MODE 3: fp32 store, K clamped to m0+BM (scores strictly causal)
// MODE 5: fp32 store (plain / split-K partial)
// z-offset: ptr += (z&3)*aZ + (z>>2)*aZ2
template <int MODE>
__global__ __launch_bounds__(256) void gemm_bt(
    const bf16* __restrict__ A, long lda, long aZ, long aZ2,
    const bf16* __restrict__ Bt, long ldb, long bZ, long bZ2,
    void* __restrict__ Cv, long ldc, long cZ,
    int M, int N, int K) {
  const int m0 = blockIdx.y * BM;
  const int n0 = blockIdx.x * BN;
  if (MODE == 2 && n0 > m0) return;  // never read downstream (MODE-3 K-clamp)
  const long z = blockIdx.z;
  A  += (z & 3) * aZ + (z >> 2) * aZ2;
  Bt += (z & 3) * bZ + (z >> 2) * bZ2;

  __shared__ __align__(16) bf16 As[BM * BK];
  __shared__ __align__(16) bf16 Bs[BN * BK];

  const int tid  = threadIdx.x;
  const int lane = tid & 63;
  const int wr   = (tid >> 6) >> 1;
  const int wc   = (tid >> 6) & 1;
  const int l15  = lane & 15;
  const int qd   = lane >> 4;

  f32x4 acc[4][4] = {};

  int Keff = K;
  if (MODE == 3) { int kc = m0 + BM; Keff = kc < K ? kc : K; }

  const int srow = tid >> 2;        // 0..63
  const int skc  = (tid & 3) * 8;   // 0,8,16,24
  const bf16* ap = A + (long)(m0 + srow) * lda + skc;
  const bf16* bp = Bt + (long)(n0 + srow) * ldb + skc;

  for (int k0 = 0; k0 < Keff; k0 += BK) {
    uint4 a0 = *(const uint4*)(ap + k0);
    uint4 a1 = *(const uint4*)(ap + k0 + 64 * lda);
    uint4 b0 = *(const uint4*)(bp + k0);
    uint4 b1 = *(const uint4*)(bp + k0 + 64 * ldb);
    __syncthreads();
    *(uint4*)&As[srow * BK + skc]        = a0;
    *(uint4*)&As[(srow + 64) * BK + skc] = a1;
    *(uint4*)&Bs[srow * BK + skc]        = b0;
    *(uint4*)&Bs[(srow + 64) * BK + skc] = b1;
    __syncthreads();
    bf16x8 af[4], bfr[4];
#pragma unroll
    for (int i = 0; i < 4; i++)
      af[i] = *(const bf16x8*)&As[(wr * 64 + i * 16 + l15) * BK + qd * 8];
#pragma unroll
    for (int j = 0; j < 4; j++)
      bfr[j] = *(const bf16x8*)&Bs[(wc * 64 + j * 16 + l15) * BK + qd * 8];
#pragma unroll
    for (int i = 0; i < 4; i++)
#pragma unroll
      for (int j = 0; j < 4; j++)
        acc[i][j] = __builtin_amdgcn_mfma_f32_16x16x32_bf16(af[i], bfr[j], acc[i][j], 0, 0, 0);
  }

#pragma unroll
  for (int i = 0; i < 4; i++) {
#pragma unroll
    for (int j = 0; j < 4; j++) {
#pragma unroll
      for (int r = 0; r < 4; r++) {
        const int row = m0 + wr * 64 + i * 16 + qd * 4 + r;
        const int col = n0 + wc * 64 + j * 16 + l15;
        float v = acc[i][j][r];
        if (MODE == 1) {
          ((bf16*)Cv)[z * cZ + (long)row * ldc + col] = (bf16)fmaxf(v, 0.f);
        } else if (MODE == 2) {
          ((bf16*)Cv)[z * cZ + (long)row * ldc + col] = (bf16)((col < row) ? v : 0.f);
        } else {  // 3, 5
          ((float*)Cv)[z * cZ + (long)row * ldc + col] = v;
        }
      }
    }
  }
}

// qr = rope(xs), one thread per rope pair; inline sincos.
// xs head-major (h,1024,8192); pair index g = h*4194304 + t*4096 + p.
// freq(pair p) = THETA^(-2p/N)/(2pi) = 2^(-p/256)/(2pi)  [THETA=2^16, N=8192]
__global__ void rope_k(const bf16* __restrict__ xs, bf16* __restrict__ qr) {
  long g = (long)blockIdx.x * 256 + threadIdx.x;
  int local = (int)(g & 4194303);
  int t = local >> 12;
  int p = local & 4095;
  float freq = exp2f(-(float)p * (1.0f / 256.0f)) * 0.15915494309189535f;
  float ph = (float)t * freq;
  ph -= floorf(ph);
  float s, c;
  sincosf(ph * 6.283185307179586f, &s, &c);
  unsigned int u = *(const unsigned int*)(xs + 2 * g);
  float e = bf2f((unsigned short)(u & 0xffffu));   // even elem
  float o = bf2f((unsigned short)(u >> 16));       // odd elem
  unsigned int w = ((unsigned int)f2bf_bits(o * c + e * s) << 16)
                 | (unsigned int)f2bf_bits(e * c - o * s);
  *(unsigned int*)(qr + 2 * g) = w;
}

// xs *= ysp (both already relu'd), in place -> xy head-major
__global__ void mul_k(bf16* __restrict__ xs, const bf16* __restrict__ ysp) {
  long i = ((long)blockIdx.x * 256 + threadIdx.x) * 8;
  bf16x8 a = *(const bf16x8*)(xs + i);
  bf16x8 b = *(const bf16x8*)(ysp + i);
  bf16x8 o;
#pragma unroll
  for (int k = 0; k < 8; k++) o[k] = (bf16)((float)a[k] * (float)b[k]);
  *(bf16x8*)(xs + i) = o;
}

// out[c][r] = bf16(in[r][c]); fp32 input
__global__ void transpose_cvt(const float* __restrict__ in, bf16* __restrict__ out,
                              int R, int C, long inZ, long outZ) {
  in += (long)blockIdx.z * inZ;
  out += (long)blockIdx.z * outZ;
  __shared__ float tile[32][33];
  int c0 = blockIdx.x * 32, r0 = blockIdx.y * 32;
  int lc = threadIdx.x & 31, lr8 = threadIdx.x >> 5;
#pragma unroll
  for (int i = 0; i < 32; i += 8)
    tile[lr8 + i][lc] = in[(long)(r0 + lr8 + i) * C + c0 + lc];
  __syncthreads();
#pragma unroll
  for (int i = 0; i < 32; i += 8)
    out[(long)(c0 + lr8 + i) * R + r0 + lc] = (bf16)tile[lc][lr8 + i];
}

__global__ void embed_ln(const int* __restrict__ idx, const float* __restrict__ embed,
                         float* __restrict__ x, bf16* __restrict__ xb,
                         bf16* __restrict__ xT) {
  int t = blockIdx.x, d = threadIdx.x;
  float v = embed[(long)idx[t] * 256 + d];
  float m = block_sum256(v) * (1.0f / 256.0f);
  float c = v - m;
  float var = block_sum256(c * c) * (1.0f / 256.0f);
  float o = c * rsqrtf(var + 1e-5f);
  x[t * 256 + d] = o;
  xb[t * 256 + d] = (bf16)o;
  xT[d * 1024 + t] = (bf16)o;
}

__global__ void ln_rows(const float* __restrict__ in, bf16* __restrict__ out) {
  int r = blockIdx.x, d = threadIdx.x;
  float v = in[(long)r * 256 + d];
  float m = block_sum256(v) * (1.0f / 256.0f);
  float c = v - m;
  float var = block_sum256(c * c) * (1.0f / 256.0f);
  out[(long)r * 256 + d] = (bf16)(c * rsqrtf(var + 1e-5f));
}

__global__ void ln_fuse(const float* __restrict__ part, float* __restrict__ x,
                        bf16* __restrict__ xb, bf16* __restrict__ xT) {
  int t = blockIdx.x, d = threadIdx.x;
  float s = 0.f;
#pragma unroll
  for (int i = 0; i < 16; i++) s += part[(long)i * 262144 + t * 256 + d];
  float m = block_sum256(s) * (1.0f / 256.0f);
  float c = s - m;
  float var = block_sum256(c * c) * (1.0f / 256.0f);
  float y = c * rsqrtf(var + 1e-5f);
  float zv = x[t * 256 + d] + y;
  m = block_sum256(zv) * (1.0f / 256.0f);
  c = zv - m;
  var = block_sum256(c * c) * (1.0f / 256.0f);
  float o = c * rsqrtf(var + 1e-5f);
  x[t * 256 + d] = o;
  xb[t * 256 + d] = (bf16)o;
  xT[d * 1024 + t] = (bf16)o;
}

extern "C" void kernel_launch(void* const* d_in, const int* in_sizes, int n_in,
                              void* d_out, int out_size, void* d_ws, size_t ws_size,
                              hipStream_t stream) {
  const int*   idx = (const int*)d_in[0];
  const float* emb = (const float*)d_in[1];
  float* out = (float*)d_out;   // fp32 logits — the round-5 fix
  char* ws  = (char*)d_ws;

  // workspace layout (bytes), ~218 MB total
  bf16*  encT  = (bf16*)(ws + 0L);            // (h,8192,256)
  bf16*  encvT = (bf16*)(ws + 16777216L);     // (h,8192,256)
  bf16*  decT  = (bf16*)(ws + 33554432L);     // (256,32768)
  bf16*  lmT   = (bf16*)(ws + 50331648L);     // (256,256)
  float* x     = (float*)(ws + 50462720L);    // (1024,256) f32
  bf16*  xb    = (bf16*)(ws + 51511296L);     // (1024,256)
  bf16*  xT    = (bf16*)(ws + 52035584L);     // (256,1024)
  bf16*  xs    = (bf16*)(ws + 52559872L);     // (h,1024,8192); becomes xy in place
  bf16*  qr    = (bf16*)(ws + 119668736L);    // (h,1024,8192); later y_sparse
  bf16*  sc    = (bf16*)(ws + 186777600L);    // (h,1024,1024)
  float* ykv   = (float*)(ws + 195166208L);   // (h,1024,256) f32
  bf16*  ykvln = (bf16*)(ws + 199360512L);    // (h,1024,256)
  float* part  = (float*)(ws + 201457664L);   // (16,1024,256) f32

  transpose_cvt<<<dim3(256, 8, 4), dim3(256), 0, stream>>>((const float*)d_in[2], encT, 256, 8192, 2097152L, 2097152L);
  transpose_cvt<<<dim3(256, 8, 4), dim3(256), 0, stream>>>((const float*)d_in[3], encvT, 256, 8192, 2097152L, 2097152L);
  transpose_cvt<<<dim3(8, 1024, 1), dim3(256), 0, stream>>>((const float*)d_in[4], decT, 32768, 256, 0L, 0L);
  transpose_cvt<<<dim3(8, 8, 1), dim3(256), 0, stream>>>((const float*)d_in[5], lmT, 256, 256, 0L, 0L);
  embed_ln<<<dim3(1024), dim3(256), 0, stream>>>(idx, emb, x, xb, xT);

  for (int l = 0; l < 6; l++) {
    // xs = relu(x @ encoder[h])
    gemm_bt<1><<<dim3(64, 8, 4), dim3(256), 0, stream>>>(
        xb, 256L, 0L, 0L, encT, 256L, 2097152L, 8388608L,
        (void*)xs, 8192L, 8388608L, 1024, 8192, 256);
    // qr = rope(xs)
    rope_k<<<dim3(65536), dim3(256), 0, stream>>>(xs, qr);
    // sc = causal(qr @ qr^T)
    gemm_bt<2><<<dim3(8, 8, 4), dim3(256), 0, stream>>>(
        qr, 8192L, 8388608L, 33554432L, qr, 8192L, 8388608L, 33554432L,
        (void*)sc, 1024L, 1048576L, 1024, 1024, 8192);
    // ykv = sc @ x (fp32, K clamped to causal extent)
    gemm_bt<3><<<dim3(2, 8, 4), dim3(256), 0, stream>>>(
        sc, 1024L, 1048576L, 4194304L, xT, 1024L, 0L, 0L,
        (void*)ykv, 256L, 262144L, 1024, 256, 1024);
    ln_rows<<<dim3(4096), dim3(256), 0, stream>>>(ykv, ykvln);
    // y_sparse = relu(ykvln @ encoder_v[h]) -> qr buffer (dead)
    gemm_bt<1><<<dim3(64, 8, 4), dim3(256), 0, stream>>>(
        ykvln, 256L, 262144L, 1048576L, encvT, 256L, 2097152L, 8388608L,
        (void*)qr, 8192L, 8388608L, 1024, 8192, 256);
    // xy = xs * y_sparse, in place (head-major)
    mul_k<<<dim3(16384), dim3(256), 0, stream>>>(xs, qr);
    // yMLP partials: split-K, z = h*4 + chunk
    gemm_bt<5><<<dim3(2, 8, 16), dim3(256), 0, stream>>>(
        xs, 8192L, 2048L, 8388608L, decT, 32768L, 2048L, 8192L,
        (void*)part, 256L, 262144L, 1024, 256, 2048);
    ln_fuse<<<dim3(1024), dim3(256), 0, stream>>>(part, x, xb, xT);
  }
  // logits = x @ lm_head -> d_out (FP32)
  gemm_bt<5><<<dim3(2, 8, 1), dim3(256), 0, stream>>>(
      xb, 256L, 0L, 0L, lmT, 256L, 0L, 0L,
      (void*)out, 256L, 0L, 1024, 256, 256);
}

// Round 7
// 1856.162 us; speedup vs baseline: 1.3239x; 1.3239x over previous
//
#include <hip/hip_runtime.h>
#include <math.h>

// ---------------------------------------------------------------------------
// BDH forward, MI355X. Round 7 = round 6 + the reduce_sc stride fix:
// gemm_bt<6> writes partials at slice*2359296 + head*589824 + tile*16384;
// round-6 reduce_sc wrongly used 589824 as the SLICE stride (it's the head
// stride) -> summed heads instead of slices -> decorrelated output. Fixed.
//
// Structure: (1) split-K x4 scores GEMM (occupancy 6%->~25%) + deterministic
// reduce; (2) rope + xy-mult fused into GEMM epilogues; (3) LDS row pad
// SW=40 elems (2-way conflicts max; free per m136).
//
// gemm_bt: C = A(MxK) * Bt(NxK)^T, 128x128 tile, BK=32, 4 waves x (4x4)
// mfma_f32_16x16x32_bf16, fp32 accum. Layouts (learn_hip m89/m91):
//   A: lane m=l%16, k=8*(l/16)+e ; B: lane n=l%16, k=8*(l/16)+e
//   D: lane reg r: row=4*(l/16)+r, col=l%16
// ---------------------------------------------------------------------------

typedef __bf16 bf16;
typedef bf16  bf16x8 __attribute__((ext_vector_type(8)));
typedef float f32x4  __attribute__((ext_vector_type(4)));

#define BM 128
#define BN 128
#define BK 32
#define SW 40   // padded LDS row stride (elements): 80B = 20 banks, 2-way max

__device__ __forceinline__ float block_sum256(float v) {
  __shared__ float sb[4];
#pragma unroll
  for (int o = 32; o > 0; o >>= 1) v += __shfl_down(v, o);
  __syncthreads();
  if ((threadIdx.x & 63) == 0) sb[threadIdx.x >> 6] = v;
  __syncthreads();
  return sb[0] + sb[1] + sb[2] + sb[3];
}

// MODE 1: relu -> xs(bf16, Cv); fused rope (inline sincos) -> qr(bf16, Dv)
// MODE 2: strict causal mask, bf16 store; tiles above diagonal skipped [fallback]
// MODE 3: fp32 store, K clamped to m0+BM (scores strictly causal)
// MODE 4: relu * xs(read Dv) -> xy bf16
// MODE 5: fp32 store (plain / split-K partial)
// MODE 6: scores split-K partial: grid(tile36, head4, slice4), fp32 compact store
// z-offset (MODE!=6): ptr += (z&3)*aZ + (z>>2)*aZ2
template <int MODE>
__global__ __launch_bounds__(256) void gemm_bt(
    const bf16* __restrict__ A, long lda, long aZ, long aZ2,
    const bf16* __restrict__ Bt, long ldb, long bZ, long bZ2,
    void* __restrict__ Cv, long ldc, long cZ,
    void* __restrict__ Dv, long dZ,
    int M, int N, int K) {
  int m0, n0;
  long z = blockIdx.z;
  if (MODE == 6) {
    const int tile = blockIdx.x, head = blockIdx.y, slice = blockIdx.z;
    const int tr = (int)((sqrtf(8.f * tile + 1.f) - 1.f) * 0.5f);
    const int tc = tile - tr * (tr + 1) / 2;
    m0 = tr * BM; n0 = tc * BN;
    A  += (long)head * aZ2 + (long)slice * aZ;
    Bt += (long)head * bZ2 + (long)slice * bZ;
  } else {
    m0 = blockIdx.y * BM;
    n0 = blockIdx.x * BN;
    if (MODE == 2 && n0 > m0) return;  // never read downstream (MODE-3 K-clamp)
    A  += (z & 3) * aZ + (z >> 2) * aZ2;
    Bt += (z & 3) * bZ + (z >> 2) * bZ2;
  }

  __shared__ __align__(16) bf16 As[BM * SW];
  __shared__ __align__(16) bf16 Bs[BN * SW];

  const int tid  = threadIdx.x;
  const int lane = tid & 63;
  const int wr   = (tid >> 6) >> 1;
  const int wc   = (tid >> 6) & 1;
  const int l15  = lane & 15;
  const int qd   = lane >> 4;

  f32x4 acc[4][4] = {};

  int Keff = K;
  if (MODE == 3) { int kc = m0 + BM; Keff = kc < K ? kc : K; }

  const int srow = tid >> 2;        // 0..63
  const int skc  = (tid & 3) * 8;   // 0,8,16,24
  const bf16* ap = A + (long)(m0 + srow) * lda + skc;
  const bf16* bp = Bt + (long)(n0 + srow) * ldb + skc;

  for (int k0 = 0; k0 < Keff; k0 += BK) {
    uint4 a0 = *(const uint4*)(ap + k0);
    uint4 a1 = *(const uint4*)(ap + k0 + 64 * lda);
    uint4 b0 = *(const uint4*)(bp + k0);
    uint4 b1 = *(const uint4*)(bp + k0 + 64 * ldb);
    __syncthreads();
    *(uint4*)&As[srow * SW + skc]        = a0;
    *(uint4*)&As[(srow + 64) * SW + skc] = a1;
    *(uint4*)&Bs[srow * SW + skc]        = b0;
    *(uint4*)&Bs[(srow + 64) * SW + skc] = b1;
    __syncthreads();
    bf16x8 af[4], bfr[4];
#pragma unroll
    for (int i = 0; i < 4; i++)
      af[i] = *(const bf16x8*)&As[(wr * 64 + i * 16 + l15) * SW + qd * 8];
#pragma unroll
    for (int j = 0; j < 4; j++)
      bfr[j] = *(const bf16x8*)&Bs[(wc * 64 + j * 16 + l15) * SW + qd * 8];
#pragma unroll
    for (int i = 0; i < 4; i++)
#pragma unroll
      for (int j = 0; j < 4; j++)
        acc[i][j] = __builtin_amdgcn_mfma_f32_16x16x32_bf16(af[i], bfr[j], acc[i][j], 0, 0, 0);
  }

#pragma unroll
  for (int i = 0; i < 4; i++) {
#pragma unroll
    for (int j = 0; j < 4; j++) {
#pragma unroll
      for (int r = 0; r < 4; r++) {
        const int row = m0 + wr * 64 + i * 16 + qd * 4 + r;
        const int col = n0 + wc * 64 + j * 16 + l15;
        float v = acc[i][j][r];
        if (MODE == 1) {
          float rv = fmaxf(v, 0.f);
          float pv = __shfl_xor(rv, 1);  // relu'd rope-pair partner (col^1, same row)
          ((bf16*)Cv)[z * cZ + (long)row * ldc + col] = (bf16)rv;
          // rope: p=col>>1, freq=2^(-p/256)/(2pi), phase=(t*freq mod 1)*2pi
          float freq = exp2f(-(float)(col >> 1) * (1.0f / 256.0f)) * 0.15915494309189535f;
          float ph = (float)row * freq;
          ph -= floorf(ph);
          float s, c;
          __sincosf(ph * 6.283185307179586f, &s, &c);
          float rot = (col & 1) ? pv : -pv;
          ((bf16*)Dv)[z * dZ + (long)row * ldc + col] = (bf16)(rv * c + rot * s);
        } else if (MODE == 2) {
          ((bf16*)Cv)[z * cZ + (long)row * ldc + col] = (bf16)((col < row) ? v : 0.f);
        } else if (MODE == 4) {
          float rv = fmaxf(v, 0.f);
          float xv = (float)((const bf16*)Dv)[z * dZ + (long)row * 8192 + col];
          ((bf16*)Cv)[z * cZ + (long)row * ldc + col] = (bf16)(rv * xv);
        } else if (MODE == 6) {
          long base = (((long)blockIdx.z * 4 + blockIdx.y) * 36 + blockIdx.x) * 16384;
          ((float*)Cv)[base + (long)(row - m0) * 128 + (col - n0)] = v;
        } else {  // 3, 5
          ((float*)Cv)[z * cZ + (long)row * ldc + col] = v;
        }
      }
    }
  }
}

// sum 4 split-K slices, apply strict-causal mask, bf16 store into sc.
// scpart layout (from gemm_bt<6>): slice*2359296 + head*589824 + tile*16384.
__global__ void reduce_sc(const float* __restrict__ scpart, bf16* __restrict__ sc) {
  const int tile = blockIdx.x, head = blockIdx.y;
  const int tr = (int)((sqrtf(8.f * tile + 1.f) - 1.f) * 0.5f);
  const int tc = tile - tr * (tr + 1) / 2;
  const long t0 = (long)head * 589824 + (long)tile * 16384;
  for (int i = threadIdx.x; i < 16384; i += 256) {
    float s = scpart[t0 + i] + scpart[t0 + 2359296 + i]
            + scpart[t0 + 2L * 2359296 + i] + scpart[t0 + 3L * 2359296 + i];
    int lr = i >> 7, lc = i & 127;
    int grow = tr * 128 + lr, gcol = tc * 128 + lc;
    sc[(long)head * 1048576 + (long)grow * 1024 + gcol] = (bf16)((gcol < grow) ? s : 0.f);
  }
}

// out[c][r] = bf16(in[r][c]); fp32 input
__global__ void transpose_cvt(const float* __restrict__ in, bf16* __restrict__ out,
                              int R, int C, long inZ, long outZ) {
  in += (long)blockIdx.z * inZ;
  out += (long)blockIdx.z * outZ;
  __shared__ float tile[32][33];
  int c0 = blockIdx.x * 32, r0 = blockIdx.y * 32;
  int lc = threadIdx.x & 31, lr8 = threadIdx.x >> 5;
#pragma unroll
  for (int i = 0; i < 32; i += 8)
    tile[lr8 + i][lc] = in[(long)(r0 + lr8 + i) * C + c0 + lc];
  __syncthreads();
#pragma unroll
  for (int i = 0; i < 32; i += 8)
    out[(long)(c0 + lr8 + i) * R + r0 + lc] = (bf16)tile[lc][lr8 + i];
}

__global__ void embed_ln(const int* __restrict__ idx, const float* __restrict__ embed,
                         float* __restrict__ x, bf16* __restrict__ xb,
                         bf16* __restrict__ xT) {
  int t = blockIdx.x, d = threadIdx.x;
  float v = embed[(long)idx[t] * 256 + d];
  float m = block_sum256(v) * (1.0f / 256.0f);
  float c = v - m;
  float var = block_sum256(c * c) * (1.0f / 256.0f);
  float o = c * rsqrtf(var + 1e-5f);
  x[t * 256 + d] = o;
  xb[t * 256 + d] = (bf16)o;
  xT[d * 1024 + t] = (bf16)o;
}

__global__ void ln_rows(const float* __restrict__ in, bf16* __restrict__ out) {
  int r = blockIdx.x, d = threadIdx.x;
  float v = in[(long)r * 256 + d];
  float m = block_sum256(v) * (1.0f / 256.0f);
  float c = v - m;
  float var = block_sum256(c * c) * (1.0f / 256.0f);
  out[(long)r * 256 + d] = (bf16)(c * rsqrtf(var + 1e-5f));
}

__global__ void ln_fuse(const float* __restrict__ part, float* __restrict__ x,
                        bf16* __restrict__ xb, bf16* __restrict__ xT) {
  int t = blockIdx.x, d = threadIdx.x;
  float s = 0.f;
#pragma unroll
  for (int i = 0; i < 16; i++) s += part[(long)i * 262144 + t * 256 + d];
  float m = block_sum256(s) * (1.0f / 256.0f);
  float c = s - m;
  float var = block_sum256(c * c) * (1.0f / 256.0f);
  float y = c * rsqrtf(var + 1e-5f);
  float zv = x[t * 256 + d] + y;
  m = block_sum256(zv) * (1.0f / 256.0f);
  c = zv - m;
  var = block_sum256(c * c) * (1.0f / 256.0f);
  float o = c * rsqrtf(var + 1e-5f);
  x[t * 256 + d] = o;
  xb[t * 256 + d] = (bf16)o;
  xT[d * 1024 + t] = (bf16)o;
}

extern "C" void kernel_launch(void* const* d_in, const int* in_sizes, int n_in,
                              void* d_out, int out_size, void* d_ws, size_t ws_size,
                              hipStream_t stream) {
  const int*   idx = (const int*)d_in[0];
  const float* emb = (const float*)d_in[1];
  float* out = (float*)d_out;   // fp32 logits
  char* ws  = (char*)d_ws;

  // workspace layout (bytes)
  bf16*  encT   = (bf16*)(ws + 0L);            // (h,8192,256)
  bf16*  encvT  = (bf16*)(ws + 16777216L);     // (h,8192,256)
  bf16*  decT   = (bf16*)(ws + 33554432L);     // (256,32768)
  bf16*  lmT    = (bf16*)(ws + 50331648L);     // (256,256)
  float* x      = (float*)(ws + 50462720L);    // (1024,256) f32
  bf16*  xb     = (bf16*)(ws + 51511296L);     // (1024,256)
  bf16*  xT     = (bf16*)(ws + 52035584L);     // (256,1024)
  bf16*  xs     = (bf16*)(ws + 52559872L);     // (h,1024,8192)
  bf16*  qr     = (bf16*)(ws + 119668736L);    // (h,1024,8192); later xy
  bf16*  sc     = (bf16*)(ws + 186777600L);    // (h,1024,1024)
  // [195166208 .. 232914944): scpart (4 slices,4 heads,36 tiles,128,128) f32.
  // ykv/ykvln/part alias inside it — all dead while scpart is live.
  float* scpart = (float*)(ws + 195166208L);
  float* ykv    = (float*)(ws + 195166208L);   // (h,1024,256) f32
  bf16*  ykvln  = (bf16*)(ws + 199360512L);    // (h,1024,256)
  float* part   = (float*)(ws + 201457664L);   // (16,1024,256) f32
  const bool big = ws_size >= 232914944UL;     // room for scpart?

  transpose_cvt<<<dim3(256, 8, 4), dim3(256), 0, stream>>>((const float*)d_in[2], encT, 256, 8192, 2097152L, 2097152L);
  transpose_cvt<<<dim3(256, 8, 4), dim3(256), 0, stream>>>((const float*)d_in[3], encvT, 256, 8192, 2097152L, 2097152L);
  transpose_cvt<<<dim3(8, 1024, 1), dim3(256), 0, stream>>>((const float*)d_in[4], decT, 32768, 256, 0L, 0L);
  transpose_cvt<<<dim3(8, 8, 1), dim3(256), 0, stream>>>((const float*)d_in[5], lmT, 256, 256, 0L, 0L);
  embed_ln<<<dim3(1024), dim3(256), 0, stream>>>(idx, emb, x, xb, xT);

  for (int l = 0; l < 6; l++) {
    // xs = relu(x @ encoder[h]); qr = rope(xs)   [fused epilogue]
    gemm_bt<1><<<dim3(64, 8, 4), dim3(256), 0, stream>>>(
        xb, 256L, 0L, 0L, encT, 256L, 2097152L, 8388608L,
        (void*)xs, 8192L, 8388608L, (void*)qr, 8388608L, 1024, 8192, 256);
    if (big) {
      // scores split-K x4 -> fp32 partials -> reduce+mask -> sc (bf16)
      gemm_bt<6><<<dim3(36, 4, 4), dim3(256), 0, stream>>>(
          qr, 8192L, 2048L, 8388608L, qr, 8192L, 2048L, 8388608L,
          (void*)scpart, 0L, 0L, (void*)0, 0L, 1024, 1024, 2048);
      reduce_sc<<<dim3(36, 4), dim3(256), 0, stream>>>(scpart, sc);
    } else {
      gemm_bt<2><<<dim3(8, 8, 4), dim3(256), 0, stream>>>(
          qr, 8192L, 8388608L, 33554432L, qr, 8192L, 8388608L, 33554432L,
          (void*)sc, 1024L, 1048576L, (void*)0, 0L, 1024, 1024, 8192);
    }
    // ykv = sc @ x (fp32, K clamped to causal extent)
    gemm_bt<3><<<dim3(2, 8, 4), dim3(256), 0, stream>>>(
        sc, 1024L, 1048576L, 4194304L, xT, 1024L, 0L, 0L,
        (void*)ykv, 256L, 262144L, (void*)0, 0L, 1024, 256, 1024);
    ln_rows<<<dim3(4096), dim3(256), 0, stream>>>(ykv, ykvln);
    // xy = xs * relu(ykvln @ encoder_v[h]) -> qr (head-major)  [fused epilogue]
    gemm_bt<4><<<dim3(64, 8, 4), dim3(256), 0, stream>>>(
        ykvln, 256L, 262144L, 1048576L, encvT, 256L, 2097152L, 8388608L,
        (void*)qr, 8192L, 8388608L, (void*)xs, 8388608L, 1024, 8192, 256);
    // yMLP partials: split-K, z = head*4 + chunk
    gemm_bt<5><<<dim3(2, 8, 16), dim3(256), 0, stream>>>(
        qr, 8192L, 2048L, 8388608L, decT, 32768L, 2048L, 8192L,
        (void*)part, 256L, 262144L, (void*)0, 0L, 1024, 256, 2048);
    ln_fuse<<<dim3(1024), dim3(256), 0, stream>>>(part, x, xb, xT);
  }
  // logits = x @ lm_head -> d_out (fp32)
  gemm_bt<5><<<dim3(2, 8, 1), dim3(256), 0, stream>>>(
      xb, 256L, 0L, 0L, lmT, 256L, 0L, 0L,
      (void*)out, 256L, 0L, (void*)0, 0L, 1024, 256, 256);
}

// Round 8
// 1800.477 us; speedup vs baseline: 1.3649x; 1.0309x over previous
//
#include <hip/hip_runtime.h>
#include <math.h>

// ---------------------------------------------------------------------------
// BDH forward, MI355X. Round 8 = round 7 + global_load_lds (width=16) staging
// in all GEMMs (m97 ladder step), SW back to 32 (unpadded — required by LDS
// DMA, and round-7 showed the pad doubled bank conflicts anyway).
//
// gemm_bt: C = A(MxK) * Bt(NxK)^T, 128x128 tile, BK=32, 4 waves x (4x4)
// mfma_f32_16x16x32_bf16, fp32 accum. Layouts (learn_hip m89/m91):
//   A: lane m=l%16, k=8*(l/16)+e ; B: lane n=l%16, k=8*(l/16)+e
//   D: lane reg r: row=4*(l/16)+r, col=l%16
// Staging: thread tid covers LDS bytes [tid*16, tid*16+16) of each 64-row
// half-tile -> per-wave base + lane*16, exactly the global_load_lds pattern.
// ---------------------------------------------------------------------------

typedef __bf16 bf16;
typedef bf16  bf16x8 __attribute__((ext_vector_type(8)));
typedef float f32x4  __attribute__((ext_vector_type(4)));

#define BM 128
#define BN 128
#define BK 32
#define SW 32   // unpadded: required for global_load_lds lane-contiguity

typedef __attribute__((address_space(3))) unsigned int lds_uint;
typedef const __attribute__((address_space(1))) unsigned int glb_uint;

__device__ __forceinline__ void ld_g2l16(const void* g, void* l) {
  __builtin_amdgcn_global_load_lds((glb_uint*)g, (lds_uint*)l, 16, 0, 0);
}

__device__ __forceinline__ float block_sum256(float v) {
  __shared__ float sb[4];
#pragma unroll
  for (int o = 32; o > 0; o >>= 1) v += __shfl_down(v, o);
  __syncthreads();
  if ((threadIdx.x & 63) == 0) sb[threadIdx.x >> 6] = v;
  __syncthreads();
  return sb[0] + sb[1] + sb[2] + sb[3];
}

// MODE 1: relu -> xs(bf16, Cv); fused rope (inline sincos) -> qr(bf16, Dv)
// MODE 2: strict causal mask, bf16 store; tiles above diagonal skipped [fallback]
// MODE 3: fp32 store, K clamped to m0+BM (scores strictly causal)
// MODE 4: relu * xs(read Dv) -> xy bf16
// MODE 5: fp32 store (plain / split-K partial)
// MODE 6: scores split-K partial: grid(tile36, head4, slice4), fp32 compact store
// z-offset (MODE!=6): ptr += (z&3)*aZ + (z>>2)*aZ2
template <int MODE>
__global__ __launch_bounds__(256) void gemm_bt(
    const bf16* __restrict__ A, long lda, long aZ, long aZ2,
    const bf16* __restrict__ Bt, long ldb, long bZ, long bZ2,
    void* __restrict__ Cv, long ldc, long cZ,
    void* __restrict__ Dv, long dZ,
    int M, int N, int K) {
  int m0, n0;
  long z = blockIdx.z;
  if (MODE == 6) {
    const int tile = blockIdx.x, head = blockIdx.y, slice = blockIdx.z;
    const int tr = (int)((sqrtf(8.f * tile + 1.f) - 1.f) * 0.5f);
    const int tc = tile - tr * (tr + 1) / 2;
    m0 = tr * BM; n0 = tc * BN;
    A  += (long)head * aZ2 + (long)slice * aZ;
    Bt += (long)head * bZ2 + (long)slice * bZ;
  } else {
    m0 = blockIdx.y * BM;
    n0 = blockIdx.x * BN;
    if (MODE == 2 && n0 > m0) return;  // never read downstream (MODE-3 K-clamp)
    A  += (z & 3) * aZ + (z >> 2) * aZ2;
    Bt += (z & 3) * bZ + (z >> 2) * bZ2;
  }

  __shared__ __align__(16) bf16 As[BM * SW];
  __shared__ __align__(16) bf16 Bs[BN * SW];

  const int tid  = threadIdx.x;
  const int lane = tid & 63;
  const int wr   = (tid >> 6) >> 1;
  const int wc   = (tid >> 6) & 1;
  const int l15  = lane & 15;
  const int qd   = lane >> 4;

  f32x4 acc[4][4] = {};

  int Keff = K;
  if (MODE == 3) { int kc = m0 + BM; Keff = kc < K ? kc : K; }

  const int srow = tid >> 2;        // 0..63
  const int skc  = (tid & 3) * 8;   // 0,8,16,24 (elements)
  const bf16* ap = A + (long)(m0 + srow) * lda + skc;
  const bf16* bp = Bt + (long)(n0 + srow) * ldb + skc;
  char* AsB = (char*)As;
  char* BsB = (char*)Bs;

  for (int k0 = 0; k0 < Keff; k0 += BK) {
    __syncthreads();  // previous iteration's ds_reads retired in all waves
    ld_g2l16(ap + k0,            AsB + tid * 16);         // A rows 0..63
    ld_g2l16(ap + k0 + 64 * lda, AsB + 4096 + tid * 16);  // A rows 64..127
    ld_g2l16(bp + k0,            BsB + tid * 16);         // B rows 0..63
    ld_g2l16(bp + k0 + 64 * ldb, BsB + 4096 + tid * 16);  // B rows 64..127
    __syncthreads();  // compiler drains vmcnt(0) before barrier -> LDS ready
    bf16x8 af[4], bfr[4];
#pragma unroll
    for (int i = 0; i < 4; i++)
      af[i] = *(const bf16x8*)&As[(wr * 64 + i * 16 + l15) * SW + qd * 8];
#pragma unroll
    for (int j = 0; j < 4; j++)
      bfr[j] = *(const bf16x8*)&Bs[(wc * 64 + j * 16 + l15) * SW + qd * 8];
#pragma unroll
    for (int i = 0; i < 4; i++)
#pragma unroll
      for (int j = 0; j < 4; j++)
        acc[i][j] = __builtin_amdgcn_mfma_f32_16x16x32_bf16(af[i], bfr[j], acc[i][j], 0, 0, 0);
  }

#pragma unroll
  for (int i = 0; i < 4; i++) {
#pragma unroll
    for (int j = 0; j < 4; j++) {
#pragma unroll
      for (int r = 0; r < 4; r++) {
        const int row = m0 + wr * 64 + i * 16 + qd * 4 + r;
        const int col = n0 + wc * 64 + j * 16 + l15;
        float v = acc[i][j][r];
        if (MODE == 1) {
          float rv = fmaxf(v, 0.f);
          float pv = __shfl_xor(rv, 1);  // relu'd rope-pair partner (col^1, same row)
          ((bf16*)Cv)[z * cZ + (long)row * ldc + col] = (bf16)rv;
          // rope: p=col>>1, freq=2^(-p/256)/(2pi), phase=(t*freq mod 1)*2pi
          float freq = exp2f(-(float)(col >> 1) * (1.0f / 256.0f)) * 0.15915494309189535f;
          float ph = (float)row * freq;
          ph -= floorf(ph);
          float s, c;
          __sincosf(ph * 6.283185307179586f, &s, &c);
          float rot = (col & 1) ? pv : -pv;
          ((bf16*)Dv)[z * dZ + (long)row * ldc + col] = (bf16)(rv * c + rot * s);
        } else if (MODE == 2) {
          ((bf16*)Cv)[z * cZ + (long)row * ldc + col] = (bf16)((col < row) ? v : 0.f);
        } else if (MODE == 4) {
          float rv = fmaxf(v, 0.f);
          float xv = (float)((const bf16*)Dv)[z * dZ + (long)row * 8192 + col];
          ((bf16*)Cv)[z * cZ + (long)row * ldc + col] = (bf16)(rv * xv);
        } else if (MODE == 6) {
          long base = (((long)blockIdx.z * 4 + blockIdx.y) * 36 + blockIdx.x) * 16384;
          ((float*)Cv)[base + (long)(row - m0) * 128 + (col - n0)] = v;
        } else {  // 3, 5
          ((float*)Cv)[z * cZ + (long)row * ldc + col] = v;
        }
      }
    }
  }
}

// sum 4 split-K slices, apply strict-causal mask, bf16 store into sc.
// scpart layout (from gemm_bt<6>): slice*2359296 + head*589824 + tile*16384.
__global__ void reduce_sc(const float* __restrict__ scpart, bf16* __restrict__ sc) {
  const int tile = blockIdx.x, head = blockIdx.y;
  const int tr = (int)((sqrtf(8.f * tile + 1.f) - 1.f) * 0.5f);
  const int tc = tile - tr * (tr + 1) / 2;
  const long t0 = (long)head * 589824 + (long)tile * 16384;
  for (int i = threadIdx.x; i < 16384; i += 256) {
    float s = scpart[t0 + i] + scpart[t0 + 2359296 + i]
            + scpart[t0 + 2L * 2359296 + i] + scpart[t0 + 3L * 2359296 + i];
    int lr = i >> 7, lc = i & 127;
    int grow = tr * 128 + lr, gcol = tc * 128 + lc;
    sc[(long)head * 1048576 + (long)grow * 1024 + gcol] = (bf16)((gcol < grow) ? s : 0.f);
  }
}

// out[c][r] = bf16(in[r][c]); fp32 input
__global__ void transpose_cvt(const float* __restrict__ in, bf16* __restrict__ out,
                              int R, int C, long inZ, long outZ) {
  in += (long)blockIdx.z * inZ;
  out += (long)blockIdx.z * outZ;
  __shared__ float tile[32][33];
  int c0 = blockIdx.x * 32, r0 = blockIdx.y * 32;
  int lc = threadIdx.x & 31, lr8 = threadIdx.x >> 5;
#pragma unroll
  for (int i = 0; i < 32; i += 8)
    tile[lr8 + i][lc] = in[(long)(r0 + lr8 + i) * C + c0 + lc];
  __syncthreads();
#pragma unroll
  for (int i = 0; i < 32; i += 8)
    out[(long)(c0 + lr8 + i) * R + r0 + lc] = (bf16)tile[lc][lr8 + i];
}

__global__ void embed_ln(const int* __restrict__ idx, const float* __restrict__ embed,
                         float* __restrict__ x, bf16* __restrict__ xb,
                         bf16* __restrict__ xT) {
  int t = blockIdx.x, d = threadIdx.x;
  float v = embed[(long)idx[t] * 256 + d];
  float m = block_sum256(v) * (1.0f / 256.0f);
  float c = v - m;
  float var = block_sum256(c * c) * (1.0f / 256.0f);
  float o = c * rsqrtf(var + 1e-5f);
  x[t * 256 + d] = o;
  xb[t * 256 + d] = (bf16)o;
  xT[d * 1024 + t] = (bf16)o;
}

__global__ void ln_rows(const float* __restrict__ in, bf16* __restrict__ out) {
  int r = blockIdx.x, d = threadIdx.x;
  float v = in[(long)r * 256 + d];
  float m = block_sum256(v) * (1.0f / 256.0f);
  float c = v - m;
  float var = block_sum256(c * c) * (1.0f / 256.0f);
  out[(long)r * 256 + d] = (bf16)(c * rsqrtf(var + 1e-5f));
}

__global__ void ln_fuse(const float* __restrict__ part, float* __restrict__ x,
                        bf16* __restrict__ xb, bf16* __restrict__ xT) {
  int t = blockIdx.x, d = threadIdx.x;
  float s = 0.f;
#pragma unroll
  for (int i = 0; i < 16; i++) s += part[(long)i * 262144 + t * 256 + d];
  float m = block_sum256(s) * (1.0f / 256.0f);
  float c = s - m;
  float var = block_sum256(c * c) * (1.0f / 256.0f);
  float y = c * rsqrtf(var + 1e-5f);
  float zv = x[t * 256 + d] + y;
  m = block_sum256(zv) * (1.0f / 256.0f);
  c = zv - m;
  var = block_sum256(c * c) * (1.0f / 256.0f);
  float o = c * rsqrtf(var + 1e-5f);
  x[t * 256 + d] = o;
  xb[t * 256 + d] = (bf16)o;
  xT[d * 1024 + t] = (bf16)o;
}

extern "C" void kernel_launch(void* const* d_in, const int* in_sizes, int n_in,
                              void* d_out, int out_size, void* d_ws, size_t ws_size,
                              hipStream_t stream) {
  const int*   idx = (const int*)d_in[0];
  const float* emb = (const float*)d_in[1];
  float* out = (float*)d_out;   // fp32 logits
  char* ws  = (char*)d_ws;

  // workspace layout (bytes)
  bf16*  encT   = (bf16*)(ws + 0L);            // (h,8192,256)
  bf16*  encvT  = (bf16*)(ws + 16777216L);     // (h,8192,256)
  bf16*  decT   = (bf16*)(ws + 33554432L);     // (256,32768)
  bf16*  lmT    = (bf16*)(ws + 50331648L);     // (256,256)
  float* x      = (float*)(ws + 50462720L);    // (1024,256) f32
  bf16*  xb     = (bf16*)(ws + 51511296L);     // (1024,256)
  bf16*  xT     = (bf16*)(ws + 52035584L);     // (256,1024)
  bf16*  xs     = (bf16*)(ws + 52559872L);     // (h,1024,8192)
  bf16*  qr     = (bf16*)(ws + 119668736L);    // (h,1024,8192); later xy
  bf16*  sc     = (bf16*)(ws + 186777600L);    // (h,1024,1024)
  // [195166208 .. 232914944): scpart (4 slices,4 heads,36 tiles,128,128) f32.
  // ykv/ykvln/part alias inside it — all dead while scpart is live.
  float* scpart = (float*)(ws + 195166208L);
  float* ykv    = (float*)(ws + 195166208L);   // (h,1024,256) f32
  bf16*  ykvln  = (bf16*)(ws + 199360512L);    // (h,1024,256)
  float* part   = (float*)(ws + 201457664L);   // (16,1024,256) f32
  const bool big = ws_size >= 232914944UL;     // room for scpart?

  transpose_cvt<<<dim3(256, 8, 4), dim3(256), 0, stream>>>((const float*)d_in[2], encT, 256, 8192, 2097152L, 2097152L);
  transpose_cvt<<<dim3(256, 8, 4), dim3(256), 0, stream>>>((const float*)d_in[3], encvT, 256, 8192, 2097152L, 2097152L);
  transpose_cvt<<<dim3(8, 1024, 1), dim3(256), 0, stream>>>((const float*)d_in[4], decT, 32768, 256, 0L, 0L);
  transpose_cvt<<<dim3(8, 8, 1), dim3(256), 0, stream>>>((const float*)d_in[5], lmT, 256, 256, 0L, 0L);
  embed_ln<<<dim3(1024), dim3(256), 0, stream>>>(idx, emb, x, xb, xT);

  for (int l = 0; l < 6; l++) {
    // xs = relu(x @ encoder[h]); qr = rope(xs)   [fused epilogue]
    gemm_bt<1><<<dim3(64, 8, 4), dim3(256), 0, stream>>>(
        xb, 256L, 0L, 0L, encT, 256L, 2097152L, 8388608L,
        (void*)xs, 8192L, 8388608L, (void*)qr, 8388608L, 1024, 8192, 256);
    if (big) {
      // scores split-K x4 -> fp32 partials -> reduce+mask -> sc (bf16)
      gemm_bt<6><<<dim3(36, 4, 4), dim3(256), 0, stream>>>(
          qr, 8192L, 2048L, 8388608L, qr, 8192L, 2048L, 8388608L,
          (void*)scpart, 0L, 0L, (void*)0, 0L, 1024, 1024, 2048);
      reduce_sc<<<dim3(36, 4), dim3(256), 0, stream>>>(scpart, sc);
    } else {
      gemm_bt<2><<<dim3(8, 8, 4), dim3(256), 0, stream>>>(
          qr, 8192L, 8388608L, 33554432L, qr, 8192L, 8388608L, 33554432L,
          (void*)sc, 1024L, 1048576L, (void*)0, 0L, 1024, 1024, 8192);
    }
    // ykv = sc @ x (fp32, K clamped to causal extent)
    gemm_bt<3><<<dim3(2, 8, 4), dim3(256), 0, stream>>>(
        sc, 1024L, 1048576L, 4194304L, xT, 1024L, 0L, 0L,
        (void*)ykv, 256L, 262144L, (void*)0, 0L, 1024, 256, 1024);
    ln_rows<<<dim3(4096), dim3(256), 0, stream>>>(ykv, ykvln);
    // xy = xs * relu(ykvln @ encoder_v[h]) -> qr (head-major)  [fused epilogue]
    gemm_bt<4><<<dim3(64, 8, 4), dim3(256), 0, stream>>>(
        ykvln, 256L, 262144L, 1048576L, encvT, 256L, 2097152L, 8388608L,
        (void*)qr, 8192L, 8388608L, (void*)xs, 8388608L, 1024, 8192, 256);
    // yMLP partials: split-K, z = head*4 + chunk
    gemm_bt<5><<<dim3(2, 8, 16), dim3(256), 0, stream>>>(
        qr, 8192L, 2048L, 8388608L, decT, 32768L, 2048L, 8192L,
        (void*)part, 256L, 262144L, (void*)0, 0L, 1024, 256, 2048);
    ln_fuse<<<dim3(1024), dim3(256), 0, stream>>>(part, x, xb, xT);
  }
  // logits = x @ lm_head -> d_out (fp32)
  gemm_bt<5><<<dim3(2, 8, 1), dim3(256), 0, stream>>>(
      xb, 256L, 0L, 0L, lmT, 256L, 0L, 0L,
      (void*)out, 256L, 0L, (void*)0, 0L, 1024, 256, 256);
}

// Round 9
// 1658.100 us; speedup vs baseline: 1.4821x; 1.0859x over previous
//
#include <hip/hip_runtime.h>
#include <math.h>

// ---------------------------------------------------------------------------
// BDH forward, MI355X. Round 9 = round 8 + XCD-locality grid permutation for
// the two fetch-bound split-K GEMMs. Round-8 counters: scores gemm moves
// 290 MB @ 3.2 TB/s = exactly its 91 us (fetch-bound); FETCH 245 MB vs 64 MB
// of input => L2 thrash because tiles of one (head,slice) combo round-robin
// across XCDs. New grid: combo in blockIdx.x (fastest) => all tiles of a
// combo hit the same XCD (id%8), per-XCD working set 64 MB -> 8 MB.
//
// gemm_bt: C = A(MxK) * Bt(NxK)^T, 128x128 tile, BK=32, 4 waves x (4x4)
// mfma_f32_16x16x32_bf16, fp32 accum. global_load_lds(16B) staging.
// Layouts (learn_hip m89/m91):
//   A: lane m=l%16, k=8*(l/16)+e ; B: lane n=l%16, k=8*(l/16)+e
//   D: lane reg r: row=4*(l/16)+r, col=l%16
// ---------------------------------------------------------------------------

typedef __bf16 bf16;
typedef bf16  bf16x8 __attribute__((ext_vector_type(8)));
typedef float f32x4  __attribute__((ext_vector_type(4)));

#define BM 128
#define BN 128
#define BK 32
#define SW 32   // unpadded: required for global_load_lds lane-contiguity

typedef __attribute__((address_space(3))) unsigned int lds_uint;
typedef const __attribute__((address_space(1))) unsigned int glb_uint;

__device__ __forceinline__ void ld_g2l16(const void* g, void* l) {
  __builtin_amdgcn_global_load_lds((glb_uint*)g, (lds_uint*)l, 16, 0, 0);
}

__device__ __forceinline__ float block_sum256(float v) {
  __shared__ float sb[4];
#pragma unroll
  for (int o = 32; o > 0; o >>= 1) v += __shfl_down(v, o);
  __syncthreads();
  if ((threadIdx.x & 63) == 0) sb[threadIdx.x >> 6] = v;
  __syncthreads();
  return sb[0] + sb[1] + sb[2] + sb[3];
}

// MODE 1: relu -> xs(bf16, Cv); fused rope (inline sincos) -> qr(bf16, Dv)
// MODE 2: strict causal mask, bf16 store; tiles above diagonal skipped [fallback]
// MODE 3: fp32 store, K clamped to m0+BM (scores strictly causal)
// MODE 4: relu * xs(read Dv) -> xy bf16
// MODE 5: fp32 store (plain / split-K partial)
// MODE 6: scores split-K partial: grid(combo16, tile36), fp32 compact store
// MODE 7: dec split-K partial: grid(combo16, tile16); combo=head*4+chunk
// z-offset (MODE<6): ptr += (z&3)*aZ + (z>>2)*aZ2
template <int MODE>
__global__ __launch_bounds__(256) void gemm_bt(
    const bf16* __restrict__ A, long lda, long aZ, long aZ2,
    const bf16* __restrict__ Bt, long ldb, long bZ, long bZ2,
    void* __restrict__ Cv, long ldc, long cZ,
    void* __restrict__ Dv, long dZ,
    int M, int N, int K) {
  int m0, n0;
  long z = blockIdx.z;
  if (MODE == 6) {
    const int combo = blockIdx.x;   // head*4+slice, FASTEST -> same-XCD tiles
    const int tile  = blockIdx.y;   // 0..35 lower-tri tile
    const int tr = (int)((sqrtf(8.f * tile + 1.f) - 1.f) * 0.5f);
    const int tc = tile - tr * (tr + 1) / 2;
    m0 = tr * BM; n0 = tc * BN;
    A  += (long)(combo >> 2) * aZ2 + (long)(combo & 3) * aZ;
    Bt += (long)(combo >> 2) * bZ2 + (long)(combo & 3) * bZ;
  } else if (MODE == 7) {
    const int combo = blockIdx.x;   // head*4+chunk, FASTEST
    z = combo;
    m0 = (blockIdx.y >> 1) * BM;
    n0 = (blockIdx.y & 1) * BN;
    A  += (combo & 3) * aZ + (combo >> 2) * aZ2;
    Bt += (combo & 3) * bZ + (combo >> 2) * bZ2;
  } else {
    m0 = blockIdx.y * BM;
    n0 = blockIdx.x * BN;
    if (MODE == 2 && n0 > m0) return;  // never read downstream (MODE-3 K-clamp)
    A  += (z & 3) * aZ + (z >> 2) * aZ2;
    Bt += (z & 3) * bZ + (z >> 2) * bZ2;
  }

  __shared__ __align__(16) bf16 As[BM * SW];
  __shared__ __align__(16) bf16 Bs[BN * SW];

  const int tid  = threadIdx.x;
  const int lane = tid & 63;
  const int wr   = (tid >> 6) >> 1;
  const int wc   = (tid >> 6) & 1;
  const int l15  = lane & 15;
  const int qd   = lane >> 4;

  f32x4 acc[4][4] = {};

  int Keff = K;
  if (MODE == 3) { int kc = m0 + BM; Keff = kc < K ? kc : K; }

  const int srow = tid >> 2;        // 0..63
  const int skc  = (tid & 3) * 8;   // 0,8,16,24 (elements)
  const bf16* ap = A + (long)(m0 + srow) * lda + skc;
  const bf16* bp = Bt + (long)(n0 + srow) * ldb + skc;
  char* AsB = (char*)As;
  char* BsB = (char*)Bs;

  for (int k0 = 0; k0 < Keff; k0 += BK) {
    __syncthreads();  // previous iteration's ds_reads retired in all waves
    ld_g2l16(ap + k0,            AsB + tid * 16);         // A rows 0..63
    ld_g2l16(ap + k0 + 64 * lda, AsB + 4096 + tid * 16);  // A rows 64..127
    ld_g2l16(bp + k0,            BsB + tid * 16);         // B rows 0..63
    ld_g2l16(bp + k0 + 64 * ldb, BsB + 4096 + tid * 16);  // B rows 64..127
    __syncthreads();  // compiler drains vmcnt(0) before barrier -> LDS ready
    bf16x8 af[4], bfr[4];
#pragma unroll
    for (int i = 0; i < 4; i++)
      af[i] = *(const bf16x8*)&As[(wr * 64 + i * 16 + l15) * SW + qd * 8];
#pragma unroll
    for (int j = 0; j < 4; j++)
      bfr[j] = *(const bf16x8*)&Bs[(wc * 64 + j * 16 + l15) * SW + qd * 8];
#pragma unroll
    for (int i = 0; i < 4; i++)
#pragma unroll
      for (int j = 0; j < 4; j++)
        acc[i][j] = __builtin_amdgcn_mfma_f32_16x16x32_bf16(af[i], bfr[j], acc[i][j], 0, 0, 0);
  }

#pragma unroll
  for (int i = 0; i < 4; i++) {
#pragma unroll
    for (int j = 0; j < 4; j++) {
#pragma unroll
      for (int r = 0; r < 4; r++) {
        const int row = m0 + wr * 64 + i * 16 + qd * 4 + r;
        const int col = n0 + wc * 64 + j * 16 + l15;
        float v = acc[i][j][r];
        if (MODE == 1) {
          float rv = fmaxf(v, 0.f);
          float pv = __shfl_xor(rv, 1);  // relu'd rope-pair partner (col^1, same row)
          ((bf16*)Cv)[z * cZ + (long)row * ldc + col] = (bf16)rv;
          // rope: p=col>>1, freq=2^(-p/256)/(2pi), phase=(t*freq mod 1)*2pi
          float freq = exp2f(-(float)(col >> 1) * (1.0f / 256.0f)) * 0.15915494309189535f;
          float ph = (float)row * freq;
          ph -= floorf(ph);
          float s, c;
          __sincosf(ph * 6.283185307179586f, &s, &c);
          float rot = (col & 1) ? pv : -pv;
          ((bf16*)Dv)[z * dZ + (long)row * ldc + col] = (bf16)(rv * c + rot * s);
        } else if (MODE == 2) {
          ((bf16*)Cv)[z * cZ + (long)row * ldc + col] = (bf16)((col < row) ? v : 0.f);
        } else if (MODE == 4) {
          float rv = fmaxf(v, 0.f);
          float xv = (float)((const bf16*)Dv)[z * dZ + (long)row * 8192 + col];
          ((bf16*)Cv)[z * cZ + (long)row * ldc + col] = (bf16)(rv * xv);
        } else if (MODE == 6) {
          const int combo = blockIdx.x;  // head*4+slice
          long base = (((long)(combo & 3) * 4 + (combo >> 2)) * 36 + blockIdx.y) * 16384;
          ((float*)Cv)[base + (long)(row - m0) * 128 + (col - n0)] = v;
        } else {  // 3, 5, 7
          ((float*)Cv)[z * cZ + (long)row * ldc + col] = v;
        }
      }
    }
  }
}

// sum 4 split-K slices, apply strict-causal mask, bf16 store into sc.
// scpart layout (from gemm_bt<6>): slice*2359296 + head*589824 + tile*16384.
__global__ void reduce_sc(const float* __restrict__ scpart, bf16* __restrict__ sc) {
  const int tile = blockIdx.x, head = blockIdx.y;
  const int tr = (int)((sqrtf(8.f * tile + 1.f) - 1.f) * 0.5f);
  const int tc = tile - tr * (tr + 1) / 2;
  const long t0 = (long)head * 589824 + (long)tile * 16384;
  for (int i = threadIdx.x; i < 16384; i += 256) {
    float s = scpart[t0 + i] + scpart[t0 + 2359296 + i]
            + scpart[t0 + 2L * 2359296 + i] + scpart[t0 + 3L * 2359296 + i];
    int lr = i >> 7, lc = i & 127;
    int grow = tr * 128 + lr, gcol = tc * 128 + lc;
    sc[(long)head * 1048576 + (long)grow * 1024 + gcol] = (bf16)((gcol < grow) ? s : 0.f);
  }
}

// out[c][r] = bf16(in[r][c]); fp32 input
__global__ void transpose_cvt(const float* __restrict__ in, bf16* __restrict__ out,
                              int R, int C, long inZ, long outZ) {
  in += (long)blockIdx.z * inZ;
  out += (long)blockIdx.z * outZ;
  __shared__ float tile[32][33];
  int c0 = blockIdx.x * 32, r0 = blockIdx.y * 32;
  int lc = threadIdx.x & 31, lr8 = threadIdx.x >> 5;
#pragma unroll
  for (int i = 0; i < 32; i += 8)
    tile[lr8 + i][lc] = in[(long)(r0 + lr8 + i) * C + c0 + lc];
  __syncthreads();
#pragma unroll
  for (int i = 0; i < 32; i += 8)
    out[(long)(c0 + lr8 + i) * R + r0 + lc] = (bf16)tile[lc][lr8 + i];
}

__global__ void embed_ln(const int* __restrict__ idx, const float* __restrict__ embed,
                         float* __restrict__ x, bf16* __restrict__ xb,
                         bf16* __restrict__ xT) {
  int t = blockIdx.x, d = threadIdx.x;
  float v = embed[(long)idx[t] * 256 + d];
  float m = block_sum256(v) * (1.0f / 256.0f);
  float c = v - m;
  float var = block_sum256(c * c) * (1.0f / 256.0f);
  float o = c * rsqrtf(var + 1e-5f);
  x[t * 256 + d] = o;
  xb[t * 256 + d] = (bf16)o;
  xT[d * 1024 + t] = (bf16)o;
}

__global__ void ln_rows(const float* __restrict__ in, bf16* __restrict__ out) {
  int r = blockIdx.x, d = threadIdx.x;
  float v = in[(long)r * 256 + d];
  float m = block_sum256(v) * (1.0f / 256.0f);
  float c = v - m;
  float var = block_sum256(c * c) * (1.0f / 256.0f);
  out[(long)r * 256 + d] = (bf16)(c * rsqrtf(var + 1e-5f));
}

__global__ void ln_fuse(const float* __restrict__ part, float* __restrict__ x,
                        bf16* __restrict__ xb, bf16* __restrict__ xT) {
  int t = blockIdx.x, d = threadIdx.x;
  float s = 0.f;
#pragma unroll
  for (int i = 0; i < 16; i++) s += part[(long)i * 262144 + t * 256 + d];
  float m = block_sum256(s) * (1.0f / 256.0f);
  float c = s - m;
  float var = block_sum256(c * c) * (1.0f / 256.0f);
  float y = c * rsqrtf(var + 1e-5f);
  float zv = x[t * 256 + d] + y;
  m = block_sum256(zv) * (1.0f / 256.0f);
  c = zv - m;
  var = block_sum256(c * c) * (1.0f / 256.0f);
  float o = c * rsqrtf(var + 1e-5f);
  x[t * 256 + d] = o;
  xb[t * 256 + d] = (bf16)o;
  xT[d * 1024 + t] = (bf16)o;
}

extern "C" void kernel_launch(void* const* d_in, const int* in_sizes, int n_in,
                              void* d_out, int out_size, void* d_ws, size_t ws_size,
                              hipStream_t stream) {
  const int*   idx = (const int*)d_in[0];
  const float* emb = (const float*)d_in[1];
  float* out = (float*)d_out;   // fp32 logits
  char* ws  = (char*)d_ws;

  // workspace layout (bytes)
  bf16*  encT   = (bf16*)(ws + 0L);            // (h,8192,256)
  bf16*  encvT  = (bf16*)(ws + 16777216L);     // (h,8192,256)
  bf16*  decT   = (bf16*)(ws + 33554432L);     // (256,32768)
  bf16*  lmT    = (bf16*)(ws + 50331648L);     // (256,256)
  float* x      = (float*)(ws + 50462720L);    // (1024,256) f32
  bf16*  xb     = (bf16*)(ws + 51511296L);     // (1024,256)
  bf16*  xT     = (bf16*)(ws + 52035584L);     // (256,1024)
  bf16*  xs     = (bf16*)(ws + 52559872L);     // (h,1024,8192)
  bf16*  qr     = (bf16*)(ws + 119668736L);    // (h,1024,8192); later xy
  bf16*  sc     = (bf16*)(ws + 186777600L);    // (h,1024,1024)
  // [195166208 .. 232914944): scpart (4 slices,4 heads,36 tiles,128,128) f32.
  // ykv/ykvln/part alias inside it — all dead while scpart is live.
  float* scpart = (float*)(ws + 195166208L);
  float* ykv    = (float*)(ws + 195166208L);   // (h,1024,256) f32
  bf16*  ykvln  = (bf16*)(ws + 199360512L);    // (h,1024,256)
  float* part   = (float*)(ws + 201457664L);   // (16,1024,256) f32
  const bool big = ws_size >= 232914944UL;     // room for scpart?

  transpose_cvt<<<dim3(256, 8, 4), dim3(256), 0, stream>>>((const float*)d_in[2], encT, 256, 8192, 2097152L, 2097152L);
  transpose_cvt<<<dim3(256, 8, 4), dim3(256), 0, stream>>>((const float*)d_in[3], encvT, 256, 8192, 2097152L, 2097152L);
  transpose_cvt<<<dim3(8, 1024, 1), dim3(256), 0, stream>>>((const float*)d_in[4], decT, 32768, 256, 0L, 0L);
  transpose_cvt<<<dim3(8, 8, 1), dim3(256), 0, stream>>>((const float*)d_in[5], lmT, 256, 256, 0L, 0L);
  embed_ln<<<dim3(1024), dim3(256), 0, stream>>>(idx, emb, x, xb, xT);

  for (int l = 0; l < 6; l++) {
    // xs = relu(x @ encoder[h]); qr = rope(xs)   [fused epilogue]
    gemm_bt<1><<<dim3(64, 8, 4), dim3(256), 0, stream>>>(
        xb, 256L, 0L, 0L, encT, 256L, 2097152L, 8388608L,
        (void*)xs, 8192L, 8388608L, (void*)qr, 8388608L, 1024, 8192, 256);
    if (big) {
      // scores split-K x4, combo-fastest grid (XCD locality) -> reduce+mask
      gemm_bt<6><<<dim3(16, 36), dim3(256), 0, stream>>>(
          qr, 8192L, 2048L, 8388608L, qr, 8192L, 2048L, 8388608L,
          (void*)scpart, 0L, 0L, (void*)0, 0L, 1024, 1024, 2048);
      reduce_sc<<<dim3(36, 4), dim3(256), 0, stream>>>(scpart, sc);
    } else {
      gemm_bt<2><<<dim3(8, 8, 4), dim3(256), 0, stream>>>(
          qr, 8192L, 8388608L, 33554432L, qr, 8192L, 8388608L, 33554432L,
          (void*)sc, 1024L, 1048576L, (void*)0, 0L, 1024, 1024, 8192);
    }
    // ykv = sc @ x (fp32, K clamped to causal extent)
    gemm_bt<3><<<dim3(2, 8, 4), dim3(256), 0, stream>>>(
        sc, 1024L, 1048576L, 4194304L, xT, 1024L, 0L, 0L,
        (void*)ykv, 256L, 262144L, (void*)0, 0L, 1024, 256, 1024);
    ln_rows<<<dim3(4096), dim3(256), 0, stream>>>(ykv, ykvln);
    // xy = xs * relu(ykvln @ encoder_v[h]) -> qr (head-major)  [fused epilogue]
    gemm_bt<4><<<dim3(64, 8, 4), dim3(256), 0, stream>>>(
        ykvln, 256L, 262144L, 1048576L, encvT, 256L, 2097152L, 8388608L,
        (void*)qr, 8192L, 8388608L, (void*)xs, 8388608L, 1024, 8192, 256);
    // yMLP partials: split-K, combo-fastest grid (XCD locality)
    gemm_bt<7><<<dim3(16, 16), dim3(256), 0, stream>>>(
        qr, 8192L, 2048L, 8388608L, decT, 32768L, 2048L, 8192L,
        (void*)part, 256L, 262144L, (void*)0, 0L, 1024, 256, 2048);
    ln_fuse<<<dim3(1024), dim3(256), 0, stream>>>(part, x, xb, xT);
  }
  // logits = x @ lm_head -> d_out (fp32)
  gemm_bt<5><<<dim3(2, 8, 1), dim3(256), 0, stream>>>(
      xb, 256L, 0L, 0L, lmT, 256L, 0L, 0L,
      (void*)out, 256L, 0L, (void*)0, 0L, 1024, 256, 256);
}